// Round 3
// baseline (133.044 us; speedup 1.0000x reference)
//
#include <hip/hip_runtime.h>
#include <hip/hip_cooperative_groups.h>

namespace cg = cooperative_groups;

// steps = 65536, channels = 6, state = [pos(6), vel(6)]
// Closed form of the scan:
//   S_t = sum_{i<=t} a_i        (per channel)
//   W_t = sum_{i<=t} i * a_i    (per channel)
//   vel[t] = v0 + dt*S_t
//   pos[t] = p0 + dt*(t+1)*v0 + dt^2*((t+0.5)*S_t - W_t)
// Output layout: states [65536,12] flat, then actions [65536,6] flat.
//
// Single cooperative kernel: phase 1 writes per-block (S,W) partials, grid
// sync, phase 2 computes the cross-block exclusive prefix (24 KB, L2-hot)
// and finishes the scan. Actions chunk stays in LDS across the sync, so the
// input is fetched from HBM exactly once. All global IO is coalesced float4.

#define STEPS   65536
#define NCH     6
#define STATE   12
#define NB      256
#define CHUNK   (STEPS / NB)        // 256 steps per block
#define BLK     (NCH * 64)          // 384 threads = 6 waves; wave w <-> channel w
#define ACT_OFF (STEPS * STATE)     // float offset of actions region in out

__global__ __launch_bounds__(BLK) void k_fused(const float4* __restrict__ act4,
                                               const float* __restrict__ x,
                                               double* __restrict__ bsum,
                                               float4* __restrict__ out4) {
    __shared__ float sIn[CHUNK * NCH];          // 6 KiB, persists across grid sync
    __shared__ float sOut[CHUNK * STATE];       // 12 KiB
    const int b = blockIdx.x, tid = threadIdx.x;

    // ---- Phase 1: stage-in (coalesced), actions passthrough, block partials.
    float4 v = act4[b * (CHUNK * NCH / 4) + tid];
    ((float4*)sIn)[tid] = v;
    out4[(ACT_OFF / 4) + b * (CHUNK * NCH / 4) + tid] = v;   // actions copy
    __syncthreads();

    const int c = tid >> 6, lane = tid & 63;
    {
        double sA = 0.0, sW = 0.0;
#pragma unroll
        for (int k = 0; k < 4; ++k) {
            const int   tl = k * 64 + lane;
            const float a  = sIn[tl * NCH + c];
            sA += (double)a;
            sW += (double)(b * CHUNK + tl) * (double)a;
        }
#pragma unroll
        for (int off = 32; off > 0; off >>= 1) {
            sA += __shfl_down(sA, off, 64);
            sW += __shfl_down(sW, off, 64);
        }
        if (lane == 0) {
            bsum[(b * NCH + c) * 2 + 0] = sA;
            bsum[(b * NCH + c) * 2 + 1] = sW;
        }
    }

    __threadfence();          // release partials device-wide (cross-XCD L2)
    cg::this_grid().sync();
    __threadfence();          // acquire

    // ---- Phase 2: cross-block exclusive prefix for this channel.
    double offA, offW;
    {
        double vA = 0.0, vW = 0.0;
#pragma unroll
        for (int k = 0; k < 4; ++k) {
            const int idx = k * 64 + lane;
            if (idx < b) {
                vA += bsum[(idx * NCH + c) * 2 + 0];
                vW += bsum[(idx * NCH + c) * 2 + 1];
            }
        }
#pragma unroll
        for (int off = 32; off > 0; off >>= 1) {
            vA += __shfl_down(vA, off, 64);
            vW += __shfl_down(vW, off, 64);
        }
        offA = __shfl(vA, 0, 64);
        offW = __shfl(vW, 0, 64);
    }

    const double dt  = (double)0.1f;   // match float32(0.1) bit pattern
    const double dt2 = dt * dt;
    const double p0  = (double)x[c];
    const double v0  = (double)x[NCH + c];

    // Chunk scan: 4 sequential 64-step wave-scans, lane <-> timestep.
    double accA = offA, accW = offW;
#pragma unroll
    for (int k = 0; k < 4; ++k) {
        const int   tl = k * 64 + lane;
        const int   t  = b * CHUNK + tl;
        const float a  = sIn[tl * NCH + c];
        double iA = (double)a;
        double iW = (double)t * (double)a;
#pragma unroll
        for (int off = 1; off < 64; off <<= 1) {
            const double uA = __shfl_up(iA, off, 64);
            const double uW = __shfl_up(iW, off, 64);
            if (lane >= off) { iA += uA; iW += uW; }
        }
        const double runA = accA + iA;
        const double runW = accW + iW;
        const double vel = v0 + dt * runA;
        const double pos = p0 + dt * (double)(t + 1) * v0
                         + dt2 * (((double)t + 0.5) * runA - runW);
        sOut[tl * STATE + c]       = (float)pos;
        sOut[tl * STATE + NCH + c] = (float)vel;
        accA += __shfl(iA, 63, 64);
        accW += __shfl(iW, 63, 64);
    }
    __syncthreads();

    // Coalesced writeout of the 256x12 state chunk: 768 float4, 2/thread.
    const float4* so4 = (const float4*)sOut;
    out4[b * (CHUNK * STATE / 4) + tid]       = so4[tid];
    out4[b * (CHUNK * STATE / 4) + BLK + tid] = so4[BLK + tid];
}

extern "C" void kernel_launch(void* const* d_in, const int* in_sizes, int n_in,
                              void* d_out, int out_size, void* d_ws, size_t ws_size,
                              hipStream_t stream) {
    const float* x       = (const float*)d_in[0];   // 12 floats: pos(6), vel(6)
    const float* actions = (const float*)d_in[1];   // [65536, 6]
    float*       out     = (float*)d_out;           // states(786432) + actions(393216)
    double*      bsum    = (double*)d_ws;           // NB*NCH*2 doubles = 24 KiB

    const float4* act4 = (const float4*)actions;
    float4*       out4 = (float4*)out;
    void* args[] = { (void*)&act4, (void*)&x, (void*)&bsum, (void*)&out4 };
    hipLaunchCooperativeKernel((const void*)k_fused, dim3(NB), dim3(BLK),
                               args, 0, stream);
}

// Round 4
// 92.370 us; speedup vs baseline: 1.4403x; 1.4403x over previous
//
#include <hip/hip_runtime.h>

// steps = 65536, channels = 6, state = [pos(6), vel(6)]
// Closed form of the scan:
//   S_t = sum_{i<=t} a_i        (per channel)
//   W_t = sum_{i<=t} i * a_i    (per channel)
//   vel[t] = v0 + dt*S_t
//   pos[t] = p0 + dt*(t+1)*v0 + dt^2*((t+0.5)*S_t - W_t)
// Output layout: states [65536,12] flat, then actions [65536,6] flat.
//
// SINGLE plain kernel, no grid sync, no atomics, no workspace: each block
// resolves its cross-block prefix by redundantly re-reading actions[0, b*CHUNK)
// (L2-resident: input is 1.5 MB vs 4 MB per-XCD L2). Reads are float4 in
// groups of 3 (= 2 whole timesteps x 6 channels), so channel->accumulator
// mapping is compile-time and wave-uniform. All global IO coalesced float4.

#define STEPS   65536
#define NCH     6
#define STATE   12
#define NB      128
#define CHUNK   (STEPS / NB)        // 512 steps per block
#define BLK     (NCH * 64)          // 384 threads = 6 waves; wave w <-> channel w
#define ACT_OFF (STEPS * STATE)     // float offset of actions region in out

#define WAVE_RED(v)                                   \
    _Pragma("unroll")                                 \
    for (int _o = 32; _o > 0; _o >>= 1) v += __shfl_down(v, _o, 64);

__global__ __launch_bounds__(BLK) void k_all(const float4* __restrict__ act4,
                                             const float* __restrict__ x,
                                             float4* __restrict__ out4) {
    __shared__ float  sIn[CHUNK * NCH];            // 12 KiB
    __shared__ float  sOut[CHUNK * STATE];         // 24 KiB
    __shared__ double sRedS[NCH][NCH + 1];         // [wave][channel]
    __shared__ double sRedW[NCH][NCH + 1];
    const int b = blockIdx.x, tid = threadIdx.x;
    const int c = tid >> 6, lane = tid & 63;

    // ---- Phase A: stage own chunk (coalesced) + actions passthrough.
#pragma unroll
    for (int k = 0; k < CHUNK * NCH / 4 / BLK; ++k) {       // 2 iters
        float4 v = act4[b * (CHUNK * NCH / 4) + k * BLK + tid];
        ((float4*)sIn)[k * BLK + tid] = v;
        out4[ACT_OFF / 4 + b * (CHUNK * NCH / 4) + k * BLK + tid] = v;
    }

    // ---- Phase B: redundant prefix over steps [0, b*CHUNK).
    // Group g = 2 timesteps (2g, 2g+1) = float4s {3g, 3g+1, 3g+2}.
    double S0 = 0, S1 = 0, S2 = 0, S3 = 0, S4 = 0, S5 = 0;
    double W0 = 0, W1 = 0, W2 = 0, W3 = 0, W4 = 0, W5 = 0;
    const int ngroups = b * (CHUNK / 2);
    for (int g = tid; g < ngroups; g += BLK) {
        const float4 f0 = act4[3 * g + 0];
        const float4 f1 = act4[3 * g + 1];
        const float4 f2 = act4[3 * g + 2];
        const double T0 = (double)(2 * g), T1 = T0 + 1.0;
        S0 += f0.x; W0 += T0 * f0.x;   // t=2g   ch0
        S1 += f0.y; W1 += T0 * f0.y;   //        ch1
        S2 += f0.z; W2 += T0 * f0.z;   //        ch2
        S3 += f0.w; W3 += T0 * f0.w;   //        ch3
        S4 += f1.x; W4 += T0 * f1.x;   //        ch4
        S5 += f1.y; W5 += T0 * f1.y;   //        ch5
        S0 += f1.z; W0 += T1 * f1.z;   // t=2g+1 ch0
        S1 += f1.w; W1 += T1 * f1.w;   //        ch1
        S2 += f2.x; W2 += T1 * f2.x;   //        ch2
        S3 += f2.y; W3 += T1 * f2.y;   //        ch3
        S4 += f2.z; W4 += T1 * f2.z;   //        ch4
        S5 += f2.w; W5 += T1 * f2.w;   //        ch5
    }
    WAVE_RED(S0); WAVE_RED(S1); WAVE_RED(S2); WAVE_RED(S3); WAVE_RED(S4); WAVE_RED(S5);
    WAVE_RED(W0); WAVE_RED(W1); WAVE_RED(W2); WAVE_RED(W3); WAVE_RED(W4); WAVE_RED(W5);
    if (lane == 0) {
        sRedS[c][0] = S0; sRedS[c][1] = S1; sRedS[c][2] = S2;
        sRedS[c][3] = S3; sRedS[c][4] = S4; sRedS[c][5] = S5;
        sRedW[c][0] = W0; sRedW[c][1] = W1; sRedW[c][2] = W2;
        sRedW[c][3] = W3; sRedW[c][4] = W4; sRedW[c][5] = W5;
    }
    __syncthreads();    // covers sIn stores AND sRed stores

    // Cross-wave combine for this wave's channel c (broadcast LDS reads).
    double offA = 0.0, offW = 0.0;
#pragma unroll
    for (int w = 0; w < NCH; ++w) { offA += sRedS[w][c]; offW += sRedW[w][c]; }

    const double dt  = (double)0.1f;   // match float32(0.1) bit pattern
    const double dt2 = dt * dt;
    const double p0  = (double)x[c];
    const double v0  = (double)x[NCH + c];

    // ---- Phase C: in-chunk scan, 8 sequential 64-step wave-scans.
    double accA = offA, accW = offW;
#pragma unroll
    for (int k = 0; k < CHUNK / 64; ++k) {
        const int   tl = k * 64 + lane;
        const int   t  = b * CHUNK + tl;
        const float a  = sIn[tl * NCH + c];
        double iA = (double)a;
        double iW = (double)t * (double)a;
#pragma unroll
        for (int off = 1; off < 64; off <<= 1) {
            const double uA = __shfl_up(iA, off, 64);
            const double uW = __shfl_up(iW, off, 64);
            if (lane >= off) { iA += uA; iW += uW; }
        }
        const double runA = accA + iA;
        const double runW = accW + iW;
        const double vel = v0 + dt * runA;
        const double pos = p0 + dt * (double)(t + 1) * v0
                         + dt2 * (((double)t + 0.5) * runA - runW);
        sOut[tl * STATE + c]       = (float)pos;
        sOut[tl * STATE + NCH + c] = (float)vel;
        accA += __shfl(iA, 63, 64);
        accW += __shfl(iW, 63, 64);
    }
    __syncthreads();

    // ---- Phase D: coalesced writeout of CHUNK x 12 states (1536 float4).
    const float4* so4 = (const float4*)sOut;
#pragma unroll
    for (int k = 0; k < CHUNK * STATE / 4 / BLK; ++k)       // 4 iters
        out4[b * (CHUNK * STATE / 4) + k * BLK + tid] = so4[k * BLK + tid];
}

extern "C" void kernel_launch(void* const* d_in, const int* in_sizes, int n_in,
                              void* d_out, int out_size, void* d_ws, size_t ws_size,
                              hipStream_t stream) {
    const float* x       = (const float*)d_in[0];   // 12 floats: pos(6), vel(6)
    const float* actions = (const float*)d_in[1];   // [65536, 6]
    float*       out     = (float*)d_out;           // states(786432) + actions(393216)

    hipLaunchKernelGGL(k_all, dim3(NB), dim3(BLK), 0, stream,
                       (const float4*)actions, x, (float4*)out);
}